// Round 14
// baseline (163.534 us; speedup 1.0000x reference)
//
#include <hip/hip_runtime.h>
#include <hip/hip_bf16.h>
#include <stdint.h>

// Problem constants (from reference): B=4096, D=768, N=8192, S=4
#define Bdim 4096
#define Ddim 768
#define Ndim 8192
#define Sdim 4

typedef __attribute__((ext_vector_type(4))) float floatx4;
typedef __attribute__((ext_vector_type(8))) int int8v;
typedef __attribute__((ext_vector_type(4))) int int4v;

// pack float4 -> 4x fp8 e4m3 (OCP on gfx950), HW RNE
__device__ inline int pack_fp8x4(float4 v) {
  int r = __builtin_amdgcn_cvt_pk_fp8_f32(v.x, v.y, 0, 0);  // low word
  r = __builtin_amdgcn_cvt_pk_fp8_f32(v.z, v.w, r, 1);      // high word
  return r;
}

// ---------------------------------------------------------------------------
// Kernel 1: fp32 -> fp8 e4m3 quantization of batch_x and cat; zero the stats
// region (incl. the done-counter); theta[s,b] = exp(batch_x[b].phi[s]) in
// fp32 (one wave per b).
// stats = [s4 (B) | denom (B) | numer (S*B) | counter+pad (64)] floats
// ---------------------------------------------------------------------------
__global__ void convert_kernel(const float* __restrict__ x,
                               const float* __restrict__ cat,
                               const float* __restrict__ phi,
                               unsigned char* __restrict__ xq,
                               unsigned char* __restrict__ catq,
                               float* __restrict__ stats,
                               float* __restrict__ theta) {
  int gid = blockIdx.x * blockDim.x + threadIdx.x;
  int stride = gridDim.x * blockDim.x;
  const int nx4 = (Bdim * Ddim) / 4;
  const int nc4 = (Ndim * Ddim) / 4;
  for (int i = gid; i < nx4; i += stride)
    ((int*)xq)[i] = pack_fp8x4(((const float4*)x)[i]);
  for (int i = gid; i < nc4; i += stride)
    ((int*)catq)[i] = pack_fp8x4(((const float4*)cat)[i]);
  if (gid < 6 * Bdim + 64) stats[gid] = 0.0f;

  // theta: one wave per batch row (fp32 — exact path, output-critical)
  int gw = gid >> 6;
  int lane = threadIdx.x & 63;
  if (gw < Bdim) {
    const float* xr = x + (size_t)gw * Ddim;
    float a0 = 0.f, a1 = 0.f, a2 = 0.f, a3 = 0.f;
    for (int d = lane; d < Ddim; d += 64) {
      float xv = xr[d];
      a0 = fmaf(xv, phi[d], a0);
      a1 = fmaf(xv, phi[Ddim + d], a1);
      a2 = fmaf(xv, phi[2 * Ddim + d], a2);
      a3 = fmaf(xv, phi[3 * Ddim + d], a3);
    }
#pragma unroll
    for (int off = 32; off > 0; off >>= 1) {
      a0 += __shfl_down(a0, off);
      a1 += __shfl_down(a1, off);
      a2 += __shfl_down(a2, off);
      a3 += __shfl_down(a3, off);
    }
    if (lane == 0) {
      theta[gw] = __expf(a0);
      theta[Bdim + gw] = __expf(a1);
      theta[2 * Bdim + gw] = __expf(a2);
      theta[3 * Bdim + gw] = __expf(a3);
    }
  }
}

// ---------------------------------------------------------------------------
// Kernel 2: MX-scaled fp8 MFMA GEMM  con[n,b] = sum_k cat[n,k]*x[b,k]
// R13-exact (58.6us measured; R9/R10/R13 pipeline variants all ~58.6-59.0
// with every pipe <30% -> structural plateau of this decomposition at
// ~2 blocks/CU; GEMM thread closed for this session).
// Register-prefetch: tile k+1 -> VGPRs during compute of tile k, then
// ds_write_b128 into the single 16KB buffers. Granule-interleaved LDS
// slot = (r>>3)*64 + g*8 + (r&7); fragment k = quad*32+j; unit E8M0
// scales; con stored fp8 [N/4, B, 4] packed dword; pow4 on fp32 acc.
// ---------------------------------------------------------------------------
__global__ __launch_bounds__(256) void gemm_bt_kernel(
    const unsigned char* __restrict__ A,    // cat fp8 [Ndim, Ddim]
    const unsigned char* __restrict__ Bm,   // x   fp8 [Bdim, Ddim]
    unsigned int* __restrict__ Cw,          // con fp8 [Ndim/4, Bdim, 4] as u32
    float* __restrict__ s4) {               // [Bdim] p4 column sums
  __shared__ unsigned char As[128 * 128];  // 16 KB, granule-interleaved
  __shared__ unsigned char Bs[128 * 128];  // 16 KB

  const int tid = threadIdx.x;
  const int wave = tid >> 6;
  const int lane = tid & 63;
  const int quad = lane >> 4;
  const int l16 = lane & 15;
  const int wm = (wave & 1) * 64;
  const int wn = (wave >> 1) * 64;
  const int m0 = blockIdx.x * 128;
  const int n0 = blockIdx.y * 128;

  floatx4 acc[4][4];
#pragma unroll
  for (int i = 0; i < 4; ++i)
#pragma unroll
    for (int j = 0; j < 4; ++j) acc[i][j] = (floatx4){0.f, 0.f, 0.f, 0.f};

  // staging: 1024 granule-slots per operand per K-tile; slot p holds
  // (row = (p>>6)*8 + (p&7), granule g = (p>>3)&7); 4 slots per thread.
  const unsigned char* a_src[4];
  const unsigned char* b_src[4];
#pragma unroll
  for (int i = 0; i < 4; ++i) {
    int p = tid + 256 * i;
    int row = ((p >> 6) << 3) + (p & 7);
    int colb = ((p >> 3) & 7) * 16;
    a_src[i] = A + (size_t)(m0 + row) * Ddim + colb;
    b_src[i] = Bm + (size_t)(n0 + row) * Ddim + colb;
  }

  // prologue: tile 0 -> regs -> LDS
  int4v areg[4], breg[4];
#pragma unroll
  for (int i = 0; i < 4; ++i) {
    areg[i] = *(const int4v*)(a_src[i]);
    breg[i] = *(const int4v*)(b_src[i]);
  }
#pragma unroll
  for (int i = 0; i < 4; ++i) {
    *(int4v*)(As + (tid + 256 * i) * 16) = areg[i];
    *(int4v*)(Bs + (tid + 256 * i) * 16) = breg[i];
  }
  __syncthreads();

  for (int kk = 0; kk < 6; ++kk) {
    if (kk < 5) {
      const int k0 = (kk + 1) * 128;
#pragma unroll
      for (int i = 0; i < 4; ++i) {
        areg[i] = *(const int4v*)(a_src[i] + k0);
        breg[i] = *(const int4v*)(b_src[i] + k0);
      }
    }

    // fragment: row r, k = quad*32..+31 = granules 2q,2q+1 ->
    // byte (r>>3)*1024 + quad*256 + (r&7)*16, and +128.
    int8v af[4], bf[4];
#pragma unroll
    for (int mi = 0; mi < 4; ++mi) {
      int r = wm + mi * 16 + l16;
      int base = ((r >> 3) << 10) + quad * 256 + (r & 7) * 16;
      int4v lo = *(const int4v*)(As + base);
      int4v hi = *(const int4v*)(As + base + 128);
      af[mi] = __builtin_shufflevector(lo, hi, 0, 1, 2, 3, 4, 5, 6, 7);
    }
#pragma unroll
    for (int ni = 0; ni < 4; ++ni) {
      int r = wn + ni * 16 + l16;
      int base = ((r >> 3) << 10) + quad * 256 + (r & 7) * 16;
      int4v lo = *(const int4v*)(Bs + base);
      int4v hi = *(const int4v*)(Bs + base + 128);
      bf[ni] = __builtin_shufflevector(lo, hi, 0, 1, 2, 3, 4, 5, 6, 7);
    }
#pragma unroll
    for (int mi = 0; mi < 4; ++mi)
#pragma unroll
      for (int ni = 0; ni < 4; ++ni)
        acc[mi][ni] = __builtin_amdgcn_mfma_scale_f32_16x16x128_f8f6f4(
            af[mi], bf[ni], acc[mi][ni], 0, 0,  // cbsz=0 (fp8), blgp=0 (fp8)
            0, 0x7f7f7f7f,                      // scale A: E8M0 1.0
            0, 0x7f7f7f7f);                     // scale B: E8M0 1.0

    __syncthreads();  // all reads of the tile done

    if (kk < 5) {
#pragma unroll
      for (int i = 0; i < 4; ++i) {
        *(int4v*)(As + (tid + 256 * i) * 16) = areg[i];
        *(int4v*)(Bs + (tid + 256 * i) * 16) = breg[i];
      }
      __syncthreads();  // LDS ready for next iter
    }
  }

  // C/D layout (16x16): col = lane&15, row = quad*4 + reg [verified].
  // acc[..][0..3] = rows 4g..4g+3 of one column -> one packed u32 at
  // word index g*Bdim + col of the [N/4, B, 4] layout.
  float cs4[4] = {0.f, 0.f, 0.f, 0.f};
#pragma unroll
  for (int mi = 0; mi < 4; ++mi)
#pragma unroll
    for (int ni = 0; ni < 4; ++ni) {
      int g = (m0 + wm + mi * 16) / 4 + quad;  // n-group index
      int col = n0 + wn + ni * 16 + l16;
      floatx4 a = acc[mi][ni];
      int w = __builtin_amdgcn_cvt_pk_fp8_f32(a[0], a[1], 0, 0);
      w = __builtin_amdgcn_cvt_pk_fp8_f32(a[2], a[3], w, 1);
      Cw[(size_t)g * Bdim + col] = (unsigned int)w;
#pragma unroll
      for (int rr = 0; rr < 4; ++rr) {
        float c2 = a[rr] * a[rr];
        cs4[ni] += c2 * c2;  // pow4 on exact fp32 acc
      }
    }
#pragma unroll
  for (int ni = 0; ni < 4; ++ni) {
    float v = cs4[ni];
    v += __shfl_xor(v, 16);
    v += __shfl_xor(v, 32);
    if (quad == 0) atomicAdd(&s4[n0 + wn + ni * 16 + l16], v);
  }
}

// ---------------------------------------------------------------------------
// Kernel 3: denom[b] += sum exp(con/norm4); numer[s,b] += y-masked sum;
// LAST block (done-counter, no spin -> deadlock-free regardless of
// scheduling) computes out[b] = sigmoid(sum_s numer*theta/denom + bias).
// Coherence chain: all cross-block data moves via device-scope atomics;
// __syncthreads() drains vmcnt(0) per wave (measured compiler behavior),
// so every wave's atomic adds are acked at the coherent point before
// thread 0 bumps the counter. No __threadfence (R3: that emitted an L2
// writeback per block, +25us). Last block reads via relaxed agent-scope
// atomic loads (L1 bypass). theta/bias arrive via stream ordering.
// ---------------------------------------------------------------------------
__global__ void expsum_kernel(const unsigned int* __restrict__ conq,
                              const float* __restrict__ s4,
                              const int* __restrict__ y,
                              float* __restrict__ denom,
                              float* __restrict__ numer,
                              const float* __restrict__ theta,
                              const float* __restrict__ bias,
                              int* __restrict__ counter,
                              float* __restrict__ out) {
  int b = blockIdx.x * 256 + threadIdx.x;
  int g0 = blockIdx.y * 64;                 // n-group range [g0, g0+64)
  int src = (g0 * 4) / (Ndim / Sdim);       // uniform per block

  float inv = 1.0f / fmaxf(sqrtf(sqrtf(s4[b])), 1e-12f);
  const unsigned int* p = conq + (size_t)g0 * Bdim + b;
  float dsum = 0.f, nsum = 0.f;
#pragma unroll 4
  for (int i = 0; i < 64; ++i) {
    unsigned int w = p[(size_t)i * Bdim];
    int4 yv = *(const int4*)(y + 4 * (g0 + i));  // wave-uniform
    float e0 = __expf(__builtin_amdgcn_cvt_f32_fp8(w, 0) * inv);
    float e1 = __expf(__builtin_amdgcn_cvt_f32_fp8(w, 1) * inv);
    float e2 = __expf(__builtin_amdgcn_cvt_f32_fp8(w, 2) * inv);
    float e3 = __expf(__builtin_amdgcn_cvt_f32_fp8(w, 3) * inv);
    dsum += e0 + e1 + e2 + e3;
    nsum += e0 * (float)yv.x + e1 * (float)yv.y + e2 * (float)yv.z +
            e3 * (float)yv.w;
  }
  atomicAdd(&denom[b], dsum);
  atomicAdd(&numer[src * Bdim + b], nsum);

  // ---- last-block finalize (no spin) ----
  __syncthreads();  // drains each wave's vmcnt(0): all atomics acked
  __shared__ int last;
  if (threadIdx.x == 0) {
    int old = __hip_atomic_fetch_add(counter, 1, __ATOMIC_RELAXED,
                                     __HIP_MEMORY_SCOPE_AGENT);
    last = (old == (int)(gridDim.x * gridDim.y) - 1);
  }
  __syncthreads();
  if (last) {
    float bv = bias[0];
    for (int col = threadIdx.x; col < Bdim; col += 256) {
      float den = __hip_atomic_load(&denom[col], __ATOMIC_RELAXED,
                                    __HIP_MEMORY_SCOPE_AGENT);
      float acc = 0.f;
#pragma unroll
      for (int si = 0; si < Sdim; ++si) {
        float nu = __hip_atomic_load(&numer[si * Bdim + col], __ATOMIC_RELAXED,
                                     __HIP_MEMORY_SCOPE_AGENT);
        acc += nu * theta[si * Bdim + col];
      }
      float z = acc / den + bv;
      out[col] = 1.0f / (1.0f + __expf(-z));
    }
  }
}

// ---------------------------------------------------------------------------
// Workspace layout (bytes):
//   catq  : Ndim*Ddim         =  6,291,456   (fp8)
//   xq    : Bdim*Ddim         =  3,145,728   (fp8)
//   conq  : Ndim*Bdim         = 33,554,432   (fp8, [N/4, B, 4] interleaved)
//   stats : (6*Bdim+64)*4     =     98,560   (s4 | denom | numer | counter)
//   theta : Sdim*Bdim*4       =     65,536
//   total ≈ 43.2 MB
// ---------------------------------------------------------------------------
extern "C" void kernel_launch(void* const* d_in, const int* in_sizes, int n_in,
                              void* d_out, int out_size, void* d_ws,
                              size_t ws_size, hipStream_t stream) {
  const float* batch_x = (const float*)d_in[0];
  const float* cat = (const float*)d_in[1];
  const int* y = (const int*)d_in[2];
  const float* phi = (const float*)d_in[3];
  const float* bias = (const float*)d_in[4];
  float* out = (float*)d_out;

  char* ws = (char*)d_ws;
  unsigned char* catq = (unsigned char*)ws;
  unsigned char* xq = catq + (size_t)Ndim * Ddim;
  unsigned int* conq = (unsigned int*)(xq + (size_t)Bdim * Ddim);
  float* stats = (float*)((unsigned char*)conq + (size_t)Ndim * Bdim);
  float* s4 = stats;
  float* denom = s4 + Bdim;
  float* numer = denom + Bdim;              // Sdim * Bdim
  int* counter = (int*)(stats + 6 * Bdim);  // zeroed by convert each call
  float* theta = stats + 6 * Bdim + 64;     // Sdim * Bdim

  convert_kernel<<<2048, 256, 0, stream>>>(batch_x, cat, phi, xq, catq, stats,
                                           theta);

  dim3 g2(Ndim / 128, Bdim / 128);
  gemm_bt_kernel<<<g2, 256, 0, stream>>>(catq, xq, conq, s4);

  dim3 g3(Bdim / 256, 32);
  expsum_kernel<<<g3, 256, 0, stream>>>(conq, s4, y, denom, numer, theta,
                                        bias, counter, out);
}

// Round 15
// 156.461 us; speedup vs baseline: 1.0452x; 1.0452x over previous
//
#include <hip/hip_runtime.h>
#include <hip/hip_bf16.h>
#include <stdint.h>

// Problem constants (from reference): B=4096, D=768, N=8192, S=4
#define Bdim 4096
#define Ddim 768
#define Ndim 8192
#define Sdim 4

typedef __attribute__((ext_vector_type(4))) float floatx4;
typedef __attribute__((ext_vector_type(8))) int int8v;
typedef __attribute__((ext_vector_type(4))) int int4v;

// pack float4 -> 4x fp8 e4m3 (OCP on gfx950), HW RNE
__device__ inline int pack_fp8x4(float4 v) {
  int r = __builtin_amdgcn_cvt_pk_fp8_f32(v.x, v.y, 0, 0);  // low word
  r = __builtin_amdgcn_cvt_pk_fp8_f32(v.z, v.w, r, 1);      // high word
  return r;
}

// ---------------------------------------------------------------------------
// FINAL CONFIG (R15 = R13-exact, best measured: 155.8us total).
// Session summary of measured facts on MI355X:
//  - GEMM plateau 58.6us: R9 (DMA+drain), R10 (dbuf+manual vmcnt), R13
//    (reg-prefetch) all within 0.7% -> latency-bound at a HW-capped
//    ~2 blocks/CU that launch_bounds cannot raise (R12).
//  - Fusions: pow4-in-GEMM wins; expsum/finalize fusion regresses
//    (R14: +8us; R3: +25us w/ per-block threadfence); cross-dispatch
//    stream ordering is the cheap coherence path on CDNA4.
//  - Precision: fp8 e4m3 inputs + MX-scaled K=128 MFMA (unit E8M0) +
//    fp8-packed con; absmax 0.0039 vs threshold 0.02 at every step.
// ---------------------------------------------------------------------------

// ---------------------------------------------------------------------------
// Kernel 1: fp32 -> fp8 e4m3 quantization of batch_x and cat; zero the stats
// region; theta[s,b] = exp(batch_x[b].phi[s]) in fp32 (one wave per b).
// stats = [s4 (B) | denom (B) | numer (S*B)] floats
// ---------------------------------------------------------------------------
__global__ void convert_kernel(const float* __restrict__ x,
                               const float* __restrict__ cat,
                               const float* __restrict__ phi,
                               unsigned char* __restrict__ xq,
                               unsigned char* __restrict__ catq,
                               float* __restrict__ stats,
                               float* __restrict__ theta) {
  int gid = blockIdx.x * blockDim.x + threadIdx.x;
  int stride = gridDim.x * blockDim.x;
  const int nx4 = (Bdim * Ddim) / 4;
  const int nc4 = (Ndim * Ddim) / 4;
  for (int i = gid; i < nx4; i += stride)
    ((int*)xq)[i] = pack_fp8x4(((const float4*)x)[i]);
  for (int i = gid; i < nc4; i += stride)
    ((int*)catq)[i] = pack_fp8x4(((const float4*)cat)[i]);
  if (gid < 6 * Bdim) stats[gid] = 0.0f;

  // theta: one wave per batch row (fp32 — exact path, output-critical)
  int gw = gid >> 6;
  int lane = threadIdx.x & 63;
  if (gw < Bdim) {
    const float* xr = x + (size_t)gw * Ddim;
    float a0 = 0.f, a1 = 0.f, a2 = 0.f, a3 = 0.f;
    for (int d = lane; d < Ddim; d += 64) {
      float xv = xr[d];
      a0 = fmaf(xv, phi[d], a0);
      a1 = fmaf(xv, phi[Ddim + d], a1);
      a2 = fmaf(xv, phi[2 * Ddim + d], a2);
      a3 = fmaf(xv, phi[3 * Ddim + d], a3);
    }
#pragma unroll
    for (int off = 32; off > 0; off >>= 1) {
      a0 += __shfl_down(a0, off);
      a1 += __shfl_down(a1, off);
      a2 += __shfl_down(a2, off);
      a3 += __shfl_down(a3, off);
    }
    if (lane == 0) {
      theta[gw] = __expf(a0);
      theta[Bdim + gw] = __expf(a1);
      theta[2 * Bdim + gw] = __expf(a2);
      theta[3 * Bdim + gw] = __expf(a3);
    }
  }
}

// ---------------------------------------------------------------------------
// Kernel 2: MX-scaled fp8 MFMA GEMM  con[n,b] = sum_k cat[n,k]*x[b,k]
// 128x128 tile, mfma_scale_f32_16x16x128_f8f6f4 (unit E8M0 scales = exact
// fp8 math at 2x rate), 6 K-iters. Register-prefetch: tile k+1 -> VGPRs
// during compute of tile k, then b128 stores into single 16KB buffers.
// Granule-interleaved LDS slot = (r>>3)*64 + g*8 + (r&7) (bank-uniform
// b128 reads); fragment k = quad*32+j; con stored fp8 [N/4, B, 4] packed
// dword per lane; pow4 fused on fp32 acc. Natural x-major grid.
// ---------------------------------------------------------------------------
__global__ __launch_bounds__(256) void gemm_bt_kernel(
    const unsigned char* __restrict__ A,    // cat fp8 [Ndim, Ddim]
    const unsigned char* __restrict__ Bm,   // x   fp8 [Bdim, Ddim]
    unsigned int* __restrict__ Cw,          // con fp8 [Ndim/4, Bdim, 4] as u32
    float* __restrict__ s4) {               // [Bdim] p4 column sums
  __shared__ unsigned char As[128 * 128];  // 16 KB, granule-interleaved
  __shared__ unsigned char Bs[128 * 128];  // 16 KB

  const int tid = threadIdx.x;
  const int wave = tid >> 6;
  const int lane = tid & 63;
  const int quad = lane >> 4;
  const int l16 = lane & 15;
  const int wm = (wave & 1) * 64;
  const int wn = (wave >> 1) * 64;
  const int m0 = blockIdx.x * 128;
  const int n0 = blockIdx.y * 128;

  floatx4 acc[4][4];
#pragma unroll
  for (int i = 0; i < 4; ++i)
#pragma unroll
    for (int j = 0; j < 4; ++j) acc[i][j] = (floatx4){0.f, 0.f, 0.f, 0.f};

  // staging: 1024 granule-slots per operand per K-tile; slot p holds
  // (row = (p>>6)*8 + (p&7), granule g = (p>>3)&7); 4 slots per thread.
  const unsigned char* a_src[4];
  const unsigned char* b_src[4];
#pragma unroll
  for (int i = 0; i < 4; ++i) {
    int p = tid + 256 * i;
    int row = ((p >> 6) << 3) + (p & 7);
    int colb = ((p >> 3) & 7) * 16;
    a_src[i] = A + (size_t)(m0 + row) * Ddim + colb;
    b_src[i] = Bm + (size_t)(n0 + row) * Ddim + colb;
  }

  // prologue: tile 0 -> regs -> LDS
  int4v areg[4], breg[4];
#pragma unroll
  for (int i = 0; i < 4; ++i) {
    areg[i] = *(const int4v*)(a_src[i]);
    breg[i] = *(const int4v*)(b_src[i]);
  }
#pragma unroll
  for (int i = 0; i < 4; ++i) {
    *(int4v*)(As + (tid + 256 * i) * 16) = areg[i];
    *(int4v*)(Bs + (tid + 256 * i) * 16) = breg[i];
  }
  __syncthreads();

  for (int kk = 0; kk < 6; ++kk) {
    if (kk < 5) {
      const int k0 = (kk + 1) * 128;
#pragma unroll
      for (int i = 0; i < 4; ++i) {
        areg[i] = *(const int4v*)(a_src[i] + k0);
        breg[i] = *(const int4v*)(b_src[i] + k0);
      }
    }

    // fragment: row r, k = quad*32..+31 = granules 2q,2q+1 ->
    // byte (r>>3)*1024 + quad*256 + (r&7)*16, and +128.
    int8v af[4], bf[4];
#pragma unroll
    for (int mi = 0; mi < 4; ++mi) {
      int r = wm + mi * 16 + l16;
      int base = ((r >> 3) << 10) + quad * 256 + (r & 7) * 16;
      int4v lo = *(const int4v*)(As + base);
      int4v hi = *(const int4v*)(As + base + 128);
      af[mi] = __builtin_shufflevector(lo, hi, 0, 1, 2, 3, 4, 5, 6, 7);
    }
#pragma unroll
    for (int ni = 0; ni < 4; ++ni) {
      int r = wn + ni * 16 + l16;
      int base = ((r >> 3) << 10) + quad * 256 + (r & 7) * 16;
      int4v lo = *(const int4v*)(Bs + base);
      int4v hi = *(const int4v*)(Bs + base + 128);
      bf[ni] = __builtin_shufflevector(lo, hi, 0, 1, 2, 3, 4, 5, 6, 7);
    }
#pragma unroll
    for (int mi = 0; mi < 4; ++mi)
#pragma unroll
      for (int ni = 0; ni < 4; ++ni)
        acc[mi][ni] = __builtin_amdgcn_mfma_scale_f32_16x16x128_f8f6f4(
            af[mi], bf[ni], acc[mi][ni], 0, 0,  // cbsz=0 (fp8), blgp=0 (fp8)
            0, 0x7f7f7f7f,                      // scale A: E8M0 1.0
            0, 0x7f7f7f7f);                     // scale B: E8M0 1.0

    __syncthreads();  // all reads of the tile done

    if (kk < 5) {
#pragma unroll
      for (int i = 0; i < 4; ++i) {
        *(int4v*)(As + (tid + 256 * i) * 16) = areg[i];
        *(int4v*)(Bs + (tid + 256 * i) * 16) = breg[i];
      }
      __syncthreads();  // LDS ready for next iter
    }
  }

  // C/D layout (16x16): col = lane&15, row = quad*4 + reg [verified].
  // acc[..][0..3] = rows 4g..4g+3 of one column -> one packed u32 at
  // word index g*Bdim + col of the [N/4, B, 4] layout.
  float cs4[4] = {0.f, 0.f, 0.f, 0.f};
#pragma unroll
  for (int mi = 0; mi < 4; ++mi)
#pragma unroll
    for (int ni = 0; ni < 4; ++ni) {
      int g = (m0 + wm + mi * 16) / 4 + quad;  // n-group index
      int col = n0 + wn + ni * 16 + l16;
      floatx4 a = acc[mi][ni];
      int w = __builtin_amdgcn_cvt_pk_fp8_f32(a[0], a[1], 0, 0);
      w = __builtin_amdgcn_cvt_pk_fp8_f32(a[2], a[3], w, 1);
      Cw[(size_t)g * Bdim + col] = (unsigned int)w;
#pragma unroll
      for (int rr = 0; rr < 4; ++rr) {
        float c2 = a[rr] * a[rr];
        cs4[ni] += c2 * c2;  // pow4 on exact fp32 acc
      }
    }
#pragma unroll
  for (int ni = 0; ni < 4; ++ni) {
    float v = cs4[ni];
    v += __shfl_xor(v, 16);
    v += __shfl_xor(v, 32);
    if (quad == 0) atomicAdd(&s4[n0 + wn + ni * 16 + l16], v);
  }
}

// ---------------------------------------------------------------------------
// Kernel 3: denom[b] += sum exp(con/norm4); numer[s,b] += y-masked sum.
// Reads fp8 [N/4, B, 4] con: one u32 = 4 n-elements per thread per iter,
// lanes on consecutive b -> 256B/wave coalesced; y via wave-uniform int4.
// norm4 >= max|fp32 con|, fp8 quantization adds <=~7% -> logits <= ~1.07:
// no max-subtraction needed. grid (16, 32). 2 atomics per thread.
// No in-kernel finalize (R14: last-block fusion regressed +8us).
// ---------------------------------------------------------------------------
__global__ void expsum_kernel(const unsigned int* __restrict__ conq,
                              const float* __restrict__ s4,
                              const int* __restrict__ y,
                              float* __restrict__ denom,
                              float* __restrict__ numer) {
  int b = blockIdx.x * 256 + threadIdx.x;
  int g0 = blockIdx.y * 64;                 // n-group range [g0, g0+64)
  int src = (g0 * 4) / (Ndim / Sdim);       // uniform per block

  float inv = 1.0f / fmaxf(sqrtf(sqrtf(s4[b])), 1e-12f);
  const unsigned int* p = conq + (size_t)g0 * Bdim + b;
  float dsum = 0.f, nsum = 0.f;
#pragma unroll 4
  for (int i = 0; i < 64; ++i) {
    unsigned int w = p[(size_t)i * Bdim];
    int4 yv = *(const int4*)(y + 4 * (g0 + i));  // wave-uniform
    float e0 = __expf(__builtin_amdgcn_cvt_f32_fp8(w, 0) * inv);
    float e1 = __expf(__builtin_amdgcn_cvt_f32_fp8(w, 1) * inv);
    float e2 = __expf(__builtin_amdgcn_cvt_f32_fp8(w, 2) * inv);
    float e3 = __expf(__builtin_amdgcn_cvt_f32_fp8(w, 3) * inv);
    dsum += e0 + e1 + e2 + e3;
    nsum += e0 * (float)yv.x + e1 * (float)yv.y + e2 * (float)yv.z +
            e3 * (float)yv.w;
  }
  atomicAdd(&denom[b], dsum);
  atomicAdd(&numer[src * Bdim + b], nsum);
}

// ---------------------------------------------------------------------------
// Kernel 4 (tiny): out[b] = sigmoid(sum_s numer[s,b]*theta[s,b]/denom[b]+bias)
// ---------------------------------------------------------------------------
__global__ void finalize_kernel(const float* __restrict__ denom,
                                const float* __restrict__ numer,
                                const float* __restrict__ theta,
                                const float* __restrict__ bias,
                                float* __restrict__ out) {
  int b = blockIdx.x * 256 + threadIdx.x;
  float acc = 0.f;
#pragma unroll
  for (int si = 0; si < Sdim; ++si)
    acc += numer[si * Bdim + b] * theta[si * Bdim + b];
  float z = acc / denom[b] + bias[0];
  out[b] = 1.0f / (1.0f + __expf(-z));
}

// ---------------------------------------------------------------------------
// Workspace layout (bytes):
//   catq  : Ndim*Ddim     =  6,291,456   (fp8)
//   xq    : Bdim*Ddim     =  3,145,728   (fp8)
//   conq  : Ndim*Bdim     = 33,554,432   (fp8, [N/4, B, 4] interleaved)
//   stats : 6*Bdim*4      =     98,304   (s4 | denom | numer)
//   theta : Sdim*Bdim*4   =     65,536
//   total ≈ 43.2 MB
// ---------------------------------------------------------------------------
extern "C" void kernel_launch(void* const* d_in, const int* in_sizes, int n_in,
                              void* d_out, int out_size, void* d_ws,
                              size_t ws_size, hipStream_t stream) {
  const float* batch_x = (const float*)d_in[0];
  const float* cat = (const float*)d_in[1];
  const int* y = (const int*)d_in[2];
  const float* phi = (const float*)d_in[3];
  const float* bias = (const float*)d_in[4];
  float* out = (float*)d_out;

  char* ws = (char*)d_ws;
  unsigned char* catq = (unsigned char*)ws;
  unsigned char* xq = catq + (size_t)Ndim * Ddim;
  unsigned int* conq = (unsigned int*)(xq + (size_t)Bdim * Ddim);
  float* stats = (float*)((unsigned char*)conq + (size_t)Ndim * Bdim);
  float* s4 = stats;
  float* denom = s4 + Bdim;
  float* numer = denom + Bdim;        // Sdim * Bdim
  float* theta = stats + 6 * Bdim;    // Sdim * Bdim

  convert_kernel<<<2048, 256, 0, stream>>>(batch_x, cat, phi, xq, catq, stats,
                                           theta);

  dim3 g2(Ndim / 128, Bdim / 128);
  gemm_bt_kernel<<<g2, 256, 0, stream>>>(catq, xq, conq, s4);

  dim3 g3(Bdim / 256, 32);
  expsum_kernel<<<g3, 256, 0, stream>>>(conq, s4, y, denom, numer);

  finalize_kernel<<<Bdim / 256, 256, 0, stream>>>(denom, numer, theta, bias,
                                                  out);
}